// Round 4
// baseline (264.777 us; speedup 1.0000x reference)
//
#include <hip/hip_runtime.h>
#include <math.h>

#define TOKENS    1024
#define IN_W      512
#define BLOCK_H   256
#define OUT_W     512
#define N_EXPERTS 64
#define TOPK      2
#define NSLOTS    (TOKENS * TOPK)
#define LIST_CAP  128          // ne ~ Binom(2048,1/64): mean 32, sigma 5.6
#define CHUNK     16           // tokens per chunk
#define NSPLIT    4            // hidden-dim splits per chunk
#define SLAB      (BLOCK_H / NSPLIT)   // 64 hidden cols per split-block
#define XPAD      516          // 512+4 floats; 2064 B row stride (16B-aligned, breaks bank alias)
#define VPAD      68           // 64+4

// ---------------------------------------------------------------------------
// Kernel 0: routing. 256 blocks x 256 threads; block handles 4 tokens
// (thread = (expert e, token tg)). mixer/noisec 256 KB hot -> L2-served.
// ---------------------------------------------------------------------------
__global__ __launch_bounds__(256) void routing_kernel(
    const float* __restrict__ x, const float* __restrict__ noise,
    const float* __restrict__ mixer, const float* __restrict__ noisec,
    int* __restrict__ eidx, float* __restrict__ esc)
{
    __shared__ float xs[4 * 512];
    __shared__ float hs[4 * 64];
    const int blk = blockIdx.x;              // tokens blk*4 .. +3
    const int tid = threadIdx.x;
    const int e   = tid & 63;
    const int tg  = tid >> 6;                // wave-uniform token id

    const float4* x4 = (const float4*)x;
    float4* xs4 = (float4*)xs;
    for (int idx = tid; idx < 4 * 128; idx += 256)
        xs4[idx] = x4[(size_t)blk * 4 * 128 + idx];
    __syncthreads();

    float am = 0.f, an = 0.f;
    const float* xp = xs + tg * 512;
    #pragma unroll 8
    for (int i = 0; i < IN_W; ++i) {
        const float xv = xp[i];                       // broadcast (wave-uniform)
        am = fmaf(xv, mixer [i * N_EXPERTS + e], am); // coalesced across e
        an = fmaf(xv, noisec[i * N_EXPERTS + e], an);
    }
    const int t = blk * 4 + tg;
    // softplus(v) = max(v,0) + log1p(exp(-|v|))
    const float sp = fmaxf(an, 0.f) + log1pf(expf(-fabsf(an)));
    hs[tg * 64 + e] = am + noise[t * N_EXPERTS + e] * sp;
    __syncthreads();

    if (tid < 4) {
        const float* h = hs + tid * 64;
        float b0 = -INFINITY, b1 = -INFINITY;
        int i0 = 0, i1 = 0;
        for (int i = 0; i < N_EXPERTS; ++i) {
            const float v = h[i];
            if (v > b0)      { b1 = b0; i1 = i0; b0 = v; i0 = i; }  // strict >: stable ties
            else if (v > b1) { b1 = v; i1 = i; }
        }
        const float z   = expf(b1 - b0);
        const float inv = 1.f / (1.f + z);
        const int tt = blk * 4 + tid;
        eidx[tt * 2 + 0] = i0;  esc[tt * 2 + 0] = inv;
        eidx[tt * 2 + 1] = i1;  esc[tt * 2 + 1] = z * inv;
    }
}

// ---------------------------------------------------------------------------
// Kernel 1: compaction — per-expert slot lists.
// ---------------------------------------------------------------------------
__global__ __launch_bounds__(256) void compact_kernel(
    const int* __restrict__ eidx, int* __restrict__ counts, int* __restrict__ lists)
{
    const int s = blockIdx.x * 256 + threadIdx.x;
    const int e = eidx[s];
    const int pos = atomicAdd(&counts[e], 1);
    if (pos < LIST_CAP) lists[e * LIST_CAP + pos] = s;
}

// ---------------------------------------------------------------------------
// Kernel 2: fused expert FFN with hidden-dim split.
// grid (4 chunk-slots, NSPLIT, 64 experts), 256 threads.
// Block (e, sp, cs) for each chunk ci = cs, cs+4, ...:
//   phase 1: v_sp = relu(x @ W1[:, sp*64:+64] + b1)   (64-col slab, LDS vs)
//   phase 2: out  += sc * (v_sp @ W2[sp*64:+64, :])   (partial over h, atomic)
// Weight slabs are disjoint across sp -> no extra weight traffic; block count
// x4 vs round 3 (latency hiding). Bias2 added by sp==0 only.
// Workspace use: ~48.5 KB metadata only.
// ---------------------------------------------------------------------------
__global__ __launch_bounds__(256) void expert_fused_kernel(
    const float* __restrict__ x,
    const float* __restrict__ w1s, const float* __restrict__ b1s,
    const float* __restrict__ w2s, const float* __restrict__ b2s,
    const int* __restrict__ counts, const int* __restrict__ lists,
    const float* __restrict__ esc, float* __restrict__ out)
{
    __shared__ float xs[CHUNK * XPAD];     // 33.0 KB
    __shared__ float vs[CHUNK * VPAD];     //  4.4 KB
    __shared__ int   slotIds[CHUNK];
    __shared__ float escv[CHUNK];
    const int e  = blockIdx.z;
    const int sp = blockIdx.y;
    const int ne = min(counts[e], LIST_CAP);
    const int nChunks = (ne + CHUNK - 1) / CHUNK;
    const int tid = threadIdx.x;

    const float4* w1v = (const float4*)(w1s + (size_t)e * IN_W * BLOCK_H);
    const float4* w2v = (const float4*)(w2s + (size_t)e * BLOCK_H * OUT_W);
    const float4* x4  = (const float4*)x;

    // phase-1 layout: c16 = float4 col within 64-col slab, tr = token
    const int c16 = tid & 15;
    const int tr  = tid >> 4;
    const int wcol1 = sp * 16 + c16;                 // float4 index in 256-col W1 row
    // phase-2 layout: c2 = float4 out col (128 of them), tr2 = token parity
    const int c2  = tid & 127;
    const int tr2 = tid >> 7;
    const float4 bias1 = ((const float4*)(b1s + (size_t)e * BLOCK_H))[wcol1];
    const float4 bias2 = ((const float4*)(b2s + (size_t)e * OUT_W))[c2];

    for (int ci = blockIdx.x; ci < nChunks; ci += gridDim.x) {
        const int c0   = ci * CHUNK;
        const int nTok = min(CHUNK, ne - c0);
        if (tid < CHUNK) {
            const int s = (tid < nTok) ? lists[e * LIST_CAP + c0 + tid] : 0;
            slotIds[tid] = s;
            escv[tid]    = esc[s];
        }
        __syncthreads();

        // stage token rows (zero-pad missing tokens)
        for (int idx = tid; idx < CHUNK * 128; idx += 256) {
            const int t = idx >> 7, q = idx & 127;
            float4 v = make_float4(0.f, 0.f, 0.f, 0.f);
            if (t < nTok) v = x4[(size_t)(slotIds[t] >> 1) * 128 + q];
            *(float4*)&xs[t * XPAD + q * 4] = v;
        }
        __syncthreads();

        // ---- phase 1: v_sp = relu(x @ W1slab + b1slab) ----
        float4 a = make_float4(0.f, 0.f, 0.f, 0.f);
        {
            const float*  xp = xs + tr * XPAD;
            const float4* wp = w1v + wcol1;
            #pragma unroll 8
            for (int i = 0; i < IN_W; ++i) {
                const float4 w  = wp[(size_t)i * 64];   // 256 B/wave, L1-shared
                const float  xv = xp[i];                // 4 banks, 16-lane bcast
                a.x = fmaf(xv, w.x, a.x);  a.y = fmaf(xv, w.y, a.y);
                a.z = fmaf(xv, w.z, a.z);  a.w = fmaf(xv, w.w, a.w);
            }
        }
        {
            float4 r;
            r.x = fmaxf(a.x + bias1.x, 0.f);  r.y = fmaxf(a.y + bias1.y, 0.f);
            r.z = fmaxf(a.z + bias1.z, 0.f);  r.w = fmaxf(a.w + bias1.w, 0.f);
            *(float4*)&vs[tr * VPAD + c16 * 4] = r;
        }
        __syncthreads();

        // ---- phase 2: out += sc * (v_sp @ W2slab [+ b2 if sp==0]) ----
        float4 acc[8];
        #pragma unroll
        for (int j = 0; j < 8; ++j) acc[j] = make_float4(0.f, 0.f, 0.f, 0.f);
        {
            const float4* wp2 = w2v + (size_t)sp * SLAB * 128 + c2;
            #pragma unroll 4
            for (int h = 0; h < SLAB; ++h) {
                const float4 w = wp2[(size_t)h * 128];  // 1 KB/wave coalesced
                #pragma unroll
                for (int j = 0; j < 8; ++j) {
                    const float vv = vs[(tr2 + 2 * j) * VPAD + h];  // broadcast
                    acc[j].x = fmaf(vv, w.x, acc[j].x);
                    acc[j].y = fmaf(vv, w.y, acc[j].y);
                    acc[j].z = fmaf(vv, w.z, acc[j].z);
                    acc[j].w = fmaf(vv, w.w, acc[j].w);
                }
            }
        }
        #pragma unroll
        for (int j = 0; j < 8; ++j) {
            const int t = tr2 + 2 * j;
            if (t < nTok) {
                const int   s  = slotIds[t];
                const float sc = escv[t];
                float4 r = acc[j];
                if (sp == 0) { r.x += bias2.x; r.y += bias2.y;
                               r.z += bias2.z; r.w += bias2.w; }
                float* o = out + (size_t)(s >> 1) * OUT_W + c2 * 4;
                atomicAdd(o + 0, r.x * sc);
                atomicAdd(o + 1, r.y * sc);
                atomicAdd(o + 2, r.z * sc);
                atomicAdd(o + 3, r.w * sc);
            }
        }
        __syncthreads();   // xs/vs/slotIds reused next chunk
    }
}

extern "C" void kernel_launch(void* const* d_in, const int* in_sizes, int n_in,
                              void* d_out, int out_size, void* d_ws, size_t ws_size,
                              hipStream_t stream) {
    const float* x      = (const float*)d_in[0];
    const float* noise  = (const float*)d_in[1];
    const float* w1s    = (const float*)d_in[2];
    const float* b1s    = (const float*)d_in[3];
    const float* w2s    = (const float*)d_in[4];
    const float* b2s    = (const float*)d_in[5];
    const float* mixer  = (const float*)d_in[6];
    const float* noisec = (const float*)d_in[7];
    float* out = (float*)d_out;

    // workspace layout — ~48.5 KB total (keep FAR under ws_size; a 2.2 MB
    // layout in round 2 overran d_ws and corrupted adjacent allocations)
    char* ws = (char*)d_ws;
    int*   counts = (int*)ws;                                   ws += 256;
    int*   eidx   = (int*)ws;                                   ws += NSLOTS * sizeof(int);
    float* esc    = (float*)ws;                                 ws += NSLOTS * sizeof(float);
    int*   lists  = (int*)ws;   /* N_EXPERTS * LIST_CAP ints = 32 KB */

    hipMemsetAsync(d_out, 0, (size_t)out_size * sizeof(float), stream);
    hipMemsetAsync(counts, 0, 256, stream);

    routing_kernel<<<TOKENS / 4, 256, 0, stream>>>(x, noise, mixer, noisec, eidx, esc);
    compact_kernel<<<NSLOTS / 256, 256, 0, stream>>>(eidx, counts, lists);
    expert_fused_kernel<<<dim3(4, NSPLIT, N_EXPERTS), 256, 0, stream>>>(
        x, w1s, b1s, w2s, b2s, counts, lists, esc, out);
}

// Round 5
// 180.368 us; speedup vs baseline: 1.4680x; 1.4680x over previous
//
#include <hip/hip_runtime.h>
#include <math.h>

#define TOKENS    1024
#define IN_W      512
#define BLOCK_H   256
#define OUT_W     512
#define N_EXPERTS 64
#define TOPK      2
#define NSLOTS    (TOKENS * TOPK)
#define LIST_CAP  128     // ne ~ Binom(2048,1/64): mean 32, sigma 5.6; 128 is +17 sigma
#define T_GRP     12      // tokens per expert-block chunk
#define NGRP      4       // groups per expert -> 64*4 = 256 blocks = 1/CU
#define XPAD      520     // x row stride (floats); 2080 B, 16B-aligned
#define OSPAD     516     // out-stage row stride; 2064 B, 16B-aligned (aliases xs)
#define VPAD      264     // v row stride; 1056 B, 16B-aligned

// ---------------------------------------------------------------------------
// Routing + fused compaction. 512 blocks x 256 threads; block = 2 tokens.
// Wave = (token tq, i-half ih): 2048 waves total (2/SIMD -> latency overlap).
// Lane = expert e; mixer/noisec reads are 256 B/wave-instr coalesced, L2-hot.
// ---------------------------------------------------------------------------
__global__ __launch_bounds__(256) void routing_kernel(
    const float* __restrict__ x, const float* __restrict__ noise,
    const float* __restrict__ mixer, const float* __restrict__ noisec,
    float* __restrict__ esc, int* __restrict__ counts, int* __restrict__ lists)
{
    __shared__ float xs[2 * 512];
    __shared__ float pm[2 * 2 * 64];   // [token][half][expert] mixer partials
    __shared__ float pn[2 * 2 * 64];
    const int blk  = blockIdx.x;       // tokens 2*blk, 2*blk+1
    const int tid  = threadIdx.x;
    const int wave = tid >> 6, lane = tid & 63;
    const int tq = wave >> 1;          // token 0/1
    const int ih = wave & 1;           // i half 0/1

    ((float4*)xs)[tid] = ((const float4*)x)[(size_t)blk * 256 + tid];
    __syncthreads();

    float am = 0.f, an = 0.f;
    const float* xp = xs + tq * 512 + ih * 256;
    const float* mp = mixer  + (size_t)(ih * 256) * 64 + lane;
    const float* np = noisec + (size_t)(ih * 256) * 64 + lane;
    #pragma unroll 8
    for (int i = 0; i < 256; ++i) {
        const float xv = xp[i];                  // wave-uniform broadcast
        am = fmaf(xv, mp[i * 64], am);           // coalesced across lanes
        an = fmaf(xv, np[i * 64], an);
    }
    pm[tq * 128 + ih * 64 + lane] = am;
    pn[tq * 128 + ih * 64 + lane] = an;
    __syncthreads();

    if (tid < 128) {
        const int e = tid & 63, tt = tid >> 6;
        const int t = blk * 2 + tt;
        const float am2 = pm[tt * 128 + e] + pm[tt * 128 + 64 + e];
        const float an2 = pn[tt * 128 + e] + pn[tt * 128 + 64 + e];
        // softplus(v) = max(v,0) + log1p(exp(-|v|))
        const float sp = fmaxf(an2, 0.f) + log1pf(expf(-fabsf(an2)));
        pm[tt * 128 + e] = am2 + noise[(size_t)t * 64 + e] * sp;  // reuse as h
    }
    __syncthreads();

    if (tid < 2) {
        const float* h = pm + tid * 128;
        float b0 = -INFINITY, b1 = -INFINITY;
        int i0 = 0, i1 = 0;
        for (int i = 0; i < N_EXPERTS; ++i) {
            const float v = h[i];
            if (v > b0)      { b1 = b0; i1 = i0; b0 = v; i0 = i; }  // strict >: stable ties
            else if (v > b1) { b1 = v; i1 = i; }
        }
        const float z   = expf(b1 - b0);
        const float inv = 1.f / (1.f + z);
        const int t = blk * 2 + tid;
        esc[t * 2 + 0] = inv;
        esc[t * 2 + 1] = z * inv;
        // fused compaction (2 atomic adds are commutative fp-int, order-safe)
        const int p0 = atomicAdd(&counts[i0], 1);
        if (p0 < LIST_CAP) lists[i0 * LIST_CAP + p0] = t * 2 + 0;
        const int p1 = atomicAdd(&counts[i1], 1);
        if (p1 < LIST_CAP) lists[i1 * LIST_CAP + p1] = t * 2 + 1;
    }
}

// ---------------------------------------------------------------------------
// Fused expert FFN. grid (64 experts, NGRP groups) -> 256 blocks = 1/CU;
// block = 1024 threads = 16 waves = 4 waves/SIMD (needs VGPR <= 128).
// Linear dispatch id = e + 64*g  ->  id%8 = e%8: the 4 sibling groups of an
// expert co-locate on one XCD (L2 dedupes their shared weight stream).
// Phase 1 (x@W1): wave = (col-quarter cq1, token-triple tt); lane covers
//   4 i-rows x 16 float4-cols -> global loads are 1 KB unique per instr;
//   i-partials reduced via shfl_xor(16,32) in-register (no LDS atomics).
// Phase 2 (v@W2): same with 2 h-rows x 32 float4-cols, shfl_xor(32).
// Epilogue: out += sc * (os + b2), one atomicAdd contribution per slot.
// ---------------------------------------------------------------------------
__global__ __launch_bounds__(1024, 4) void expert_kernel(
    const float* __restrict__ x,
    const float* __restrict__ w1s, const float* __restrict__ b1s,
    const float* __restrict__ w2s, const float* __restrict__ b2s,
    const int* __restrict__ counts, const int* __restrict__ lists,
    const float* __restrict__ esc, float* __restrict__ out)
{
    __shared__ __align__(16) float smem[T_GRP * XPAD];  // xs, then os (aliased)
    __shared__ __align__(16) float vsm[T_GRP * VPAD];
    __shared__ int   slotIds[T_GRP];
    __shared__ float escv[T_GRP];

    const int e  = blockIdx.x;
    const int g  = blockIdx.y;
    const int ne = min(counts[e], LIST_CAP);
    const int tid  = threadIdx.x;
    const int wave = tid >> 6, lane = tid & 63;

    // phase-1 roles
    const int cq1  = wave & 3;                  // 64-col quarter of 256
    const int tt   = wave >> 2;                 // token triple (3 tokens)
    const int c4_1 = cq1 * 16 + (lane & 15);    // float4 col in [0,64)
    const int r1   = lane >> 4;                 // i-row offset 0..3
    // phase-2 roles
    const int c4_2 = cq1 * 32 + (lane & 31);    // float4 col in [0,128)
    const int r2   = lane >> 5;                 // h-row offset 0..1
    const int t0   = tt * 3;

    const float4* w1v = (const float4*)(w1s + (size_t)e * IN_W * BLOCK_H);
    const float4* w2v = (const float4*)(w2s + (size_t)e * BLOCK_H * OUT_W);
    const float4* b1v = (const float4*)(b1s + (size_t)e * BLOCK_H);
    const float4* b2v = (const float4*)(b2s + (size_t)e * OUT_W);
    const float4* x4  = (const float4*)x;

    for (int base = g * T_GRP; base < ne; base += NGRP * T_GRP) {
        const int nTok = min(T_GRP, ne - base);
        if (tid < T_GRP) {
            const int s = (tid < nTok) ? lists[e * LIST_CAP + base + tid] : 0;
            slotIds[tid] = s;
            escv[tid]    = esc[s];
        }
        __syncthreads();

        // stage 12 token rows (zero-pad missing)
        for (int idx = tid; idx < T_GRP * 128; idx += 1024) {
            const int t = idx >> 7, q = idx & 127;
            float4 v = make_float4(0.f, 0.f, 0.f, 0.f);
            if (t < nTok) v = x4[(size_t)(slotIds[t] >> 1) * 128 + q];
            *(float4*)&smem[t * XPAD + q * 4] = v;
        }
        __syncthreads();

        // ---- phase 1: v = relu(x @ W1 + b1) ----
        float4 a0 = make_float4(0.f, 0.f, 0.f, 0.f), a1 = a0, a2 = a0;
        {
            const float4* wp = w1v + (size_t)(r1 * 64 + c4_1);
            const float* xb0 = smem + (t0 + 0) * XPAD + r1;
            const float* xb1 = smem + (t0 + 1) * XPAD + r1;
            const float* xb2 = smem + (t0 + 2) * XPAD + r1;
            #pragma unroll 4
            for (int i = 0; i < IN_W; i += 4) {
                const float4 w = wp[(size_t)i * 64];    // 4 rows x 16 cols = 1 KB/wave
                const float xv0 = xb0[i], xv1 = xb1[i], xv2 = xb2[i];
                a0.x = fmaf(xv0, w.x, a0.x); a0.y = fmaf(xv0, w.y, a0.y);
                a0.z = fmaf(xv0, w.z, a0.z); a0.w = fmaf(xv0, w.w, a0.w);
                a1.x = fmaf(xv1, w.x, a1.x); a1.y = fmaf(xv1, w.y, a1.y);
                a1.z = fmaf(xv1, w.z, a1.z); a1.w = fmaf(xv1, w.w, a1.w);
                a2.x = fmaf(xv2, w.x, a2.x); a2.y = fmaf(xv2, w.y, a2.y);
                a2.z = fmaf(xv2, w.z, a2.z); a2.w = fmaf(xv2, w.w, a2.w);
            }
        }
        // reduce partials across r1 lane-groups (xor 16, then 32)
        #pragma unroll
        for (int m = 16; m <= 32; m <<= 1) {
            a0.x += __shfl_xor(a0.x, m); a0.y += __shfl_xor(a0.y, m);
            a0.z += __shfl_xor(a0.z, m); a0.w += __shfl_xor(a0.w, m);
            a1.x += __shfl_xor(a1.x, m); a1.y += __shfl_xor(a1.y, m);
            a1.z += __shfl_xor(a1.z, m); a1.w += __shfl_xor(a1.w, m);
            a2.x += __shfl_xor(a2.x, m); a2.y += __shfl_xor(a2.y, m);
            a2.z += __shfl_xor(a2.z, m); a2.w += __shfl_xor(a2.w, m);
        }
        if (lane < 16) {
            const float4 bb = b1v[c4_1];
            float4 r;
            r.x = fmaxf(a0.x + bb.x, 0.f); r.y = fmaxf(a0.y + bb.y, 0.f);
            r.z = fmaxf(a0.z + bb.z, 0.f); r.w = fmaxf(a0.w + bb.w, 0.f);
            *(float4*)&vsm[(t0 + 0) * VPAD + c4_1 * 4] = r;
            r.x = fmaxf(a1.x + bb.x, 0.f); r.y = fmaxf(a1.y + bb.y, 0.f);
            r.z = fmaxf(a1.z + bb.z, 0.f); r.w = fmaxf(a1.w + bb.w, 0.f);
            *(float4*)&vsm[(t0 + 1) * VPAD + c4_1 * 4] = r;
            r.x = fmaxf(a2.x + bb.x, 0.f); r.y = fmaxf(a2.y + bb.y, 0.f);
            r.z = fmaxf(a2.z + bb.z, 0.f); r.w = fmaxf(a2.w + bb.w, 0.f);
            *(float4*)&vsm[(t0 + 2) * VPAD + c4_1 * 4] = r;
        }
        __syncthreads();   // xs fully consumed; os may now alias it

        // ---- phase 2: os = v @ W2 (partials over 2-row split) ----
        float4 o0 = make_float4(0.f, 0.f, 0.f, 0.f), o1 = o0, o2 = o0;
        {
            const float4* wp2 = w2v + (size_t)(r2 * 128 + c4_2);
            const float* vb0 = vsm + (t0 + 0) * VPAD + r2;
            const float* vb1 = vsm + (t0 + 1) * VPAD + r2;
            const float* vb2 = vsm + (t0 + 2) * VPAD + r2;
            #pragma unroll 4
            for (int h = 0; h < BLOCK_H; h += 2) {
                const float4 w = wp2[(size_t)h * 128];  // 2 rows x 32 cols = 1 KB/wave
                const float v0 = vb0[h], v1 = vb1[h], v2 = vb2[h];
                o0.x = fmaf(v0, w.x, o0.x); o0.y = fmaf(v0, w.y, o0.y);
                o0.z = fmaf(v0, w.z, o0.z); o0.w = fmaf(v0, w.w, o0.w);
                o1.x = fmaf(v1, w.x, o1.x); o1.y = fmaf(v1, w.y, o1.y);
                o1.z = fmaf(v1, w.z, o1.z); o1.w = fmaf(v1, w.w, o1.w);
                o2.x = fmaf(v2, w.x, o2.x); o2.y = fmaf(v2, w.y, o2.y);
                o2.z = fmaf(v2, w.z, o2.z); o2.w = fmaf(v2, w.w, o2.w);
            }
        }
        o0.x += __shfl_xor(o0.x, 32); o0.y += __shfl_xor(o0.y, 32);
        o0.z += __shfl_xor(o0.z, 32); o0.w += __shfl_xor(o0.w, 32);
        o1.x += __shfl_xor(o1.x, 32); o1.y += __shfl_xor(o1.y, 32);
        o1.z += __shfl_xor(o1.z, 32); o1.w += __shfl_xor(o1.w, 32);
        o2.x += __shfl_xor(o2.x, 32); o2.y += __shfl_xor(o2.y, 32);
        o2.z += __shfl_xor(o2.z, 32); o2.w += __shfl_xor(o2.w, 32);
        if (lane < 32) {
            *(float4*)&smem[(t0 + 0) * OSPAD + c4_2 * 4] = o0;
            *(float4*)&smem[(t0 + 1) * OSPAD + c4_2 * 4] = o1;
            *(float4*)&smem[(t0 + 2) * OSPAD + c4_2 * 4] = o2;
        }
        __syncthreads();

        // ---- epilogue: out += sc * (os + b2), one contribution per slot ----
        for (int idx = tid; idx < T_GRP * 128; idx += 1024) {
            const int t = idx >> 7, q = idx & 127;
            if (t < nTok) {
                const float4 r  = *(const float4*)&smem[t * OSPAD + q * 4];
                const float4 bb = b2v[q];
                const float  sc = escv[t];
                float* o = out + (size_t)(slotIds[t] >> 1) * OUT_W + q * 4;
                atomicAdd(o + 0, (r.x + bb.x) * sc);
                atomicAdd(o + 1, (r.y + bb.y) * sc);
                atomicAdd(o + 2, (r.z + bb.z) * sc);
                atomicAdd(o + 3, (r.w + bb.w) * sc);
            }
        }
        __syncthreads();   // smem/vsm reused next chunk (rare: ne > 48)
    }
}

extern "C" void kernel_launch(void* const* d_in, const int* in_sizes, int n_in,
                              void* d_out, int out_size, void* d_ws, size_t ws_size,
                              hipStream_t stream) {
    const float* x      = (const float*)d_in[0];
    const float* noise  = (const float*)d_in[1];
    const float* w1s    = (const float*)d_in[2];
    const float* b1s    = (const float*)d_in[3];
    const float* w2s    = (const float*)d_in[4];
    const float* b2s    = (const float*)d_in[5];
    const float* mixer  = (const float*)d_in[6];
    const float* noisec = (const float*)d_in[7];
    float* out = (float*)d_out;

    // workspace: ~41 KB total (keep FAR under ws_size; a 2.2 MB layout in
    // round 2 overran d_ws and corrupted adjacent allocations)
    char* ws = (char*)d_ws;
    int*   counts = (int*)ws;                       ws += 256;
    float* esc    = (float*)ws;                     ws += NSLOTS * sizeof(float);
    int*   lists  = (int*)ws;   /* 64 * 128 ints = 32 KB */

    hipMemsetAsync(d_out, 0, (size_t)out_size * sizeof(float), stream);
    hipMemsetAsync(counts, 0, 256, stream);

    routing_kernel<<<TOKENS / 2, 256, 0, stream>>>(x, noise, mixer, noisec,
                                                   esc, counts, lists);
    expert_kernel<<<dim3(N_EXPERTS, NGRP), 1024, 0, stream>>>(
        x, w1s, b1s, w2s, b2s, counts, lists, esc, out);
}